// Round 2
// baseline (1865.612 us; speedup 1.0000x reference)
//
#include <hip/hip_runtime.h>
#include <stdint.h>

typedef __bf16 bf16x8 __attribute__((ext_vector_type(8)));
typedef float  f32x4  __attribute__((ext_vector_type(4)));

__device__ __forceinline__ uint16_t f2b(float f) {
  uint32_t u = __float_as_uint(f);
  return (uint16_t)((u + 0x7FFFu + ((u >> 16) & 1u)) >> 16);
}
__device__ __forceinline__ float b2f(uint16_t h) {
  return __uint_as_float(((uint32_t)h) << 16);
}
__device__ __forceinline__ uint4 pack8f(float4 a, float4 b) {
  uint4 r;
  r.x = (uint32_t)f2b(a.x) | ((uint32_t)f2b(a.y) << 16);
  r.y = (uint32_t)f2b(a.z) | ((uint32_t)f2b(a.w) << 16);
  r.z = (uint32_t)f2b(b.x) | ((uint32_t)f2b(b.y) << 16);
  r.w = (uint32_t)f2b(b.z) | ((uint32_t)f2b(b.w) << 16);
  return r;
}

// -------------------------------------------------------------------------
// Dtype detector: if W_proj is bf16-packed, low 16 bits of each u32 word are a
// plausible N(0,0.02) bf16 sample (~99.6% in (1e-4,0.5)); if fp32, low bits are
// mantissa noise (~5% pass). flag=1 -> bf16 buffers, flag=0 -> fp32 buffers.
__global__ void detect_kernel(const uint32_t* __restrict__ wproj, int* flag) {
  __shared__ int cnt;
  if (threadIdx.x == 0) cnt = 0;
  __syncthreads();
  int local = 0;
  for (int i = threadIdx.x; i < 1024; i += 256) {
    float v = __uint_as_float((wproj[i] & 0xFFFFu) << 16);
    float av = fabsf(v);
    if (av > 1e-4f && av < 0.5f) local++;
  }
  atomicAdd(&cnt, local);
  __syncthreads();
  if (threadIdx.x == 0) flag[0] = (cnt > 512) ? 1 : 0;
}

// Convert n elements (n % 2048 == 0) to canonical bf16. One thread = 8 elems.
__global__ void convert_kernel(const void* __restrict__ src,
                               uint16_t* __restrict__ dst,
                               const int* __restrict__ flagp) {
  int i = blockIdx.x * 256 + threadIdx.x;
  if (*flagp) {
    ((uint4*)dst)[i] = ((const uint4*)src)[i];
  } else {
    const float* s = (const float*)src + (size_t)i * 8;
    ((uint4*)dst)[i] = pack8f(*(const float4*)s, *(const float4*)(s + 4));
  }
}

// word[b,:] = embed_table[start_ids[b], :]  -> bf16 [512,512]
__global__ void word_kernel(const int* __restrict__ ids,
                            const void* __restrict__ embed,
                            uint16_t* __restrict__ word,
                            const int* __restrict__ flagp) {
  int c = blockIdx.x * 256 + threadIdx.x;  // 32768 chunks of 8 elems
  int b = c >> 6, off = c & 63;
  size_t row = (size_t)ids[b] * 512;
  if (*flagp) {
    ((uint4*)word)[c] = ((const uint4*)((const uint16_t*)embed + row))[off];
  } else {
    const float* s = (const float*)embed + row + (size_t)off * 8;
    ((uint4*)word)[c] = pack8f(*(const float4*)s, *(const float4*)(s + 4));
  }
}

// bias2[j] = b_ih[j] + b_hh[j] + sum_f b_proj[f] * W_ih[j,f]
__global__ void bias2_kernel(const void* __restrict__ bih,
                             const void* __restrict__ bhh,
                             const void* __restrict__ bproj,
                             const uint16_t* __restrict__ Wihb,
                             float* __restrict__ bias2,
                             const int* __restrict__ flagp) {
  int j = blockIdx.x * 256 + threadIdx.x;  // 2048
  int fl = *flagp;
  float s;
  if (fl) s = b2f(((const uint16_t*)bih)[j]) + b2f(((const uint16_t*)bhh)[j]);
  else    s = ((const float*)bih)[j] + ((const float*)bhh)[j];
  const uint16_t* wrow = Wihb + (size_t)j * 1024;
  float acc = 0.f;
  for (int f = 0; f < 512; f++) {
    float bp = fl ? b2f(((const uint16_t*)bproj)[f]) : ((const float*)bproj)[f];
    acc += bp * b2f(wrow[f]);
  }
  bias2[j] = s + acc;
}

// -------------------------------------------------------------------------
// C[M,N] = A[M,K] @ Bt[N,K]^T  (bf16 in, fp32 acc), 128x128 tile, BK=32.
// MODE 0: C bf16 row-major (ldc).
// MODE 1: chunked xgates: local row m -> b=m>>4, t0=m&15; A row = b*80+c0+t0;
//         C row t0*512+b, ldc=2048, += wg[b*2048+col], fp32 store.
// MODE 2: C fp32 (ldc), += wg[col].
// APOLY: A dtype per *flagp (0 -> fp32, converted on the fly).
template <int MODE, bool APOLY>
__global__ __launch_bounds__(256, 2)
void gemm_bt(const void* __restrict__ Av, int lda,
             const uint16_t* __restrict__ Bt, int ldb,
             void* __restrict__ Cout, int ldc, int K,
             const float* __restrict__ wg,
             const int* __restrict__ flagp, int c0) {
  __shared__ __align__(16) uint16_t As[128 * 32];
  __shared__ __align__(16) uint16_t Bs[128 * 32];
  const int tid = threadIdx.x;
  const int bm = blockIdx.y * 128, bn = blockIdx.x * 128;
  const int wid = tid >> 6, lane = tid & 63;
  const int wm = (wid >> 1) * 64, wn = (wid & 1) * 64;
  const int lrow = lane & 15, quad = lane >> 4;
  const int srow = tid >> 2, scol = (tid & 3) * 8;
  const bool a_bf16 = APOLY ? (*flagp != 0) : true;

  int r0 = bm + srow, r1 = bm + 64 + srow;
  size_t gr0, gr1;
  if (MODE == 1) {
    gr0 = (size_t)(r0 >> 4) * 80 + c0 + (r0 & 15);
    gr1 = (size_t)(r1 >> 4) * 80 + c0 + (r1 & 15);
  } else {
    gr0 = r0; gr1 = r1;
  }
  f32x4 acc[4][4] = {};

  for (int kb = 0; kb < K; kb += 32) {
    uint4 a0, a1;
    if (a_bf16) {
      a0 = *(const uint4*)((const uint16_t*)Av + gr0 * lda + kb + scol);
      a1 = *(const uint4*)((const uint16_t*)Av + gr1 * lda + kb + scol);
    } else {
      const float* p0 = (const float*)Av + gr0 * lda + kb + scol;
      const float* p1 = (const float*)Av + gr1 * lda + kb + scol;
      a0 = pack8f(*(const float4*)p0, *(const float4*)(p0 + 4));
      a1 = pack8f(*(const float4*)p1, *(const float4*)(p1 + 4));
    }
    uint4 b0 = *(const uint4*)(Bt + (size_t)(bn + srow) * ldb + kb + scol);
    uint4 b1 = *(const uint4*)(Bt + (size_t)(bn + 64 + srow) * ldb + kb + scol);
    __syncthreads();
    *(uint4*)(As + srow * 32 + scol) = a0;
    *(uint4*)(As + (64 + srow) * 32 + scol) = a1;
    *(uint4*)(Bs + srow * 32 + scol) = b0;
    *(uint4*)(Bs + (64 + srow) * 32 + scol) = b1;
    __syncthreads();
    bf16x8 af[4], bfr[4];
#pragma unroll
    for (int i = 0; i < 4; i++) {
      af[i]  = *reinterpret_cast<const bf16x8*>(As + (wm + i * 16 + lrow) * 32 + quad * 8);
      bfr[i] = *reinterpret_cast<const bf16x8*>(Bs + (wn + i * 16 + lrow) * 32 + quad * 8);
    }
#pragma unroll
    for (int i = 0; i < 4; i++)
#pragma unroll
      for (int j = 0; j < 4; j++)
        acc[i][j] = __builtin_amdgcn_mfma_f32_16x16x32_bf16(af[i], bfr[j], acc[i][j], 0, 0, 0);
  }

  if constexpr (MODE == 0) {
    uint16_t* C = (uint16_t*)Cout;
#pragma unroll
    for (int i = 0; i < 4; i++) {
      int row = bm + wm + i * 16 + quad * 4;
#pragma unroll
      for (int j = 0; j < 4; j++) {
        int col = bn + wn + j * 16 + lrow;
#pragma unroll
        for (int r = 0; r < 4; r++)
          C[(size_t)(row + r) * ldc + col] = f2b(acc[i][j][r]);
      }
    }
  } else if constexpr (MODE == 2) {
    float* C = (float*)Cout;
#pragma unroll
    for (int i = 0; i < 4; i++) {
      int row = bm + wm + i * 16 + quad * 4;
#pragma unroll
      for (int j = 0; j < 4; j++) {
        int col = bn + wn + j * 16 + lrow;
        float bias = wg[col];
#pragma unroll
        for (int r = 0; r < 4; r++)
          C[(size_t)(row + r) * ldc + col] = acc[i][j][r] + bias;
      }
    }
  } else {  // MODE 1
    float* C = (float*)Cout;
#pragma unroll
    for (int i = 0; i < 4; i++) {
#pragma unroll
      for (int r = 0; r < 4; r++) {
        int m = bm + wm + i * 16 + quad * 4 + r;
        int b = m >> 4, t0 = m & 15;
        size_t orow = (size_t)t0 * 512 + b;
#pragma unroll
        for (int j = 0; j < 4; j++) {
          int col = bn + wn + j * 16 + lrow;
          C[orow * 2048 + col] = acc[i][j][r] + wg[(size_t)b * 2048 + col];
        }
      }
    }
  }
}

// -------------------------------------------------------------------------
// One LSTM step. Grid (16,8): 64 batch rows x 32 h cols per WG; wave = gate.
__global__ __launch_bounds__(256)
void step_kernel(const uint16_t* __restrict__ hprev,  // [512,512] bf16
                 uint16_t* __restrict__ hnext,        // [512,512] bf16
                 float* __restrict__ cst,             // [512,512] fp32
                 const uint16_t* __restrict__ Whh,    // [2048,512] bf16
                 const float* __restrict__ xg_t,      // [512,2048] fp32
                 void* __restrict__ out, int t,
                 const int* __restrict__ flagp) {
  __shared__ __align__(16) uint16_t As[64 * 32];
  __shared__ __align__(16) uint16_t Bs[128 * 32];
  __shared__ float Gs[4][64][32];
  const int tid = threadIdx.x;
  const int bx = blockIdx.x * 32;
  const int by = blockIdx.y * 64;
  const int wid = tid >> 6, lane = tid & 63;
  const int lrow = lane & 15, quad = lane >> 4;
  const int srow = tid >> 2, scol = (tid & 3) * 8;
  const int g0 = srow >> 5, l0 = srow & 31;
  const int r1 = 64 + srow, g1 = r1 >> 5, l1 = r1 & 31;
  f32x4 acc[4][2] = {};

  for (int kb = 0; kb < 512; kb += 32) {
    uint4 a0 = *(const uint4*)(hprev + (size_t)(by + srow) * 512 + kb + scol);
    uint4 b0 = *(const uint4*)(Whh + (size_t)(g0 * 512 + bx + l0) * 512 + kb + scol);
    uint4 b1 = *(const uint4*)(Whh + (size_t)(g1 * 512 + bx + l1) * 512 + kb + scol);
    __syncthreads();
    *(uint4*)(As + srow * 32 + scol) = a0;
    *(uint4*)(Bs + srow * 32 + scol) = b0;
    *(uint4*)(Bs + r1 * 32 + scol) = b1;
    __syncthreads();
    bf16x8 af[4], bfr[2];
#pragma unroll
    for (int i = 0; i < 4; i++)
      af[i] = *reinterpret_cast<const bf16x8*>(As + (i * 16 + lrow) * 32 + quad * 8);
#pragma unroll
    for (int j = 0; j < 2; j++)
      bfr[j] = *reinterpret_cast<const bf16x8*>(Bs + (wid * 32 + j * 16 + lrow) * 32 + quad * 8);
#pragma unroll
    for (int i = 0; i < 4; i++)
#pragma unroll
      for (int j = 0; j < 2; j++)
        acc[i][j] = __builtin_amdgcn_mfma_f32_16x16x32_bf16(af[i], bfr[j], acc[i][j], 0, 0, 0);
  }

#pragma unroll
  for (int i = 0; i < 4; i++)
#pragma unroll
    for (int j = 0; j < 2; j++)
#pragma unroll
      for (int r = 0; r < 4; r++)
        Gs[wid][i * 16 + quad * 4 + r][j * 16 + lrow] = acc[i][j][r];
  __syncthreads();

  const int fl = *flagp;
  const int col = tid & 31;
#pragma unroll
  for (int i = 0; i < 8; i++) {
    int row = (tid >> 5) + i * 8;
    int b = by + row, hh = bx + col;
    const float* xr = xg_t + (size_t)b * 2048 + hh;
    float pi = Gs[0][row][col] + xr[0];
    float pf = Gs[1][row][col] + xr[512];
    float pg = Gs[2][row][col] + xr[1024];
    float po = Gs[3][row][col] + xr[1536];
    float si = 1.f / (1.f + expf(-pi));
    float sf = 1.f / (1.f + expf(-pf));
    float so = 1.f / (1.f + expf(-po));
    float tg = tanhf(pg);
    size_t ci = (size_t)b * 512 + hh;
    float cn = sf * cst[ci] + si * tg;
    cst[ci] = cn;
    float hn = so * tanhf(cn);
    hnext[ci] = f2b(hn);
    size_t oi = (size_t)b * 80 * 512 + (size_t)t * 512 + hh;
    if (fl) ((uint16_t*)out)[oi] = f2b(hn);
    else    ((float*)out)[oi] = hn;
  }
}

// -------------------------------------------------------------------------
extern "C" void kernel_launch(void* const* d_in, const int* in_sizes, int n_in,
                              void* d_out, int out_size, void* d_ws, size_t ws_size,
                              hipStream_t stream) {
  const void* enc   = d_in[0];            // [512,80,1024]
  const int*  ids   = (const int*)d_in[1];
  const void* Wproj = d_in[2];            // [1024,512]
  const void* bproj = d_in[3];
  const void* embed = d_in[4];            // [10000,512]
  const void* Wih   = d_in[5];            // [2048,1024]
  const void* Whh   = d_in[6];            // [2048,512]
  const void* bih   = d_in[7];
  const void* bhh   = d_in[8];

  uint8_t* w = (uint8_t*)d_ws;
  int*      flag   = (int*)w;                    // 16 KB reserved
  float*    bias2  = (float*)(w + 16384);        // 8 KB
  float*    wgates = (float*)(w + 32768);        // [512,2048] f32, 4 MB
  uint16_t* combT  = (uint16_t*)(w + 4227072);   // [2048,1024] bf16, 4 MB
  uint16_t* Wihb   = (uint16_t*)(w + 8421376);   // [2048,1024] bf16, 4 MB
  uint16_t* Whhb   = (uint16_t*)(w + 12615680);  // [2048,512] bf16, 2 MB
  uint16_t* Wprojb = (uint16_t*)(w + 14712832);  // [1024,512] bf16, 1 MB
  uint16_t* word   = (uint16_t*)(w + 15761408);  // [512,512] bf16, 512 KB
  uint16_t* hbuf0  = (uint16_t*)(w + 16285696);  // 512 KB
  uint16_t* hbuf1  = (uint16_t*)(w + 16809984);  // 512 KB
  float*    cst    = (float*)(w + 17334272);     // [512,512] f32, 1 MB
  float*    xgbuf  = (float*)(w + 18382848);     // [16,512,2048] f32, 64 MB -> ends ~85.5 MB

  detect_kernel<<<1, 256, 0, stream>>>((const uint32_t*)Wproj, flag);
  convert_kernel<<<1024, 256, 0, stream>>>(Wih, Wihb, flag);     // 2M elems
  convert_kernel<<<512, 256, 0, stream>>>(Whh, Whhb, flag);      // 1M
  convert_kernel<<<256, 256, 0, stream>>>(Wproj, Wprojb, flag);  // 512K
  word_kernel<<<128, 256, 0, stream>>>(ids, embed, word, flag);
  bias2_kernel<<<8, 256, 0, stream>>>(bih, bhh, bproj, Wihb, bias2, flag);

  // combT[j,d] = sum_f W_ih[j,f] * W_proj[d,f]   (M=2048,N=1024,K=512)
  gemm_bt<0, false><<<dim3(8, 16), 256, 0, stream>>>(Wihb, 1024, Wprojb, 512,
                                                     combT, 1024, 512, nullptr, flag, 0);
  // wgates[b,j] = sum_w word[b,w]*W_ih[j,512+w] + bias2[j]  (M=512,N=2048,K=512)
  gemm_bt<2, false><<<dim3(16, 4), 256, 0, stream>>>(word, 512, Wihb + 512, 1024,
                                                     wgates, 2048, 512, bias2, flag, 0);

  (void)hipMemsetAsync(hbuf0, 0, 512 * 512 * 2, stream);
  (void)hipMemsetAsync(cst, 0, 512 * 512 * 4, stream);

  for (int c = 0; c < 5; c++) {
    // xgbuf[t0,b,j] = sum_d enc[b,c*16+t0,d]*combT[j,d] + wgates[b,j]
    gemm_bt<1, true><<<dim3(16, 64), 256, 0, stream>>>(enc, 1024, combT, 1024,
                                                       xgbuf, 2048, 1024, wgates, flag, c * 16);
    for (int k = 0; k < 16; k++) {
      int t = c * 16 + k;
      const uint16_t* hp = (t & 1) ? hbuf1 : hbuf0;
      uint16_t* hn = (t & 1) ? hbuf0 : hbuf1;
      step_kernel<<<dim3(16, 8), 256, 0, stream>>>(hp, hn, cst, Whhb,
                                                   xgbuf + (size_t)(t & 15) * 512 * 2048,
                                                   d_out, t, flag);
    }
  }
}